// Round 3
// baseline (415.530 us; speedup 1.0000x reference)
//
#include <hip/hip_runtime.h>

#define TT 512

typedef short short8 __attribute__((ext_vector_type(8)));
typedef float f32x4 __attribute__((ext_vector_type(4)));

__device__ __forceinline__ unsigned short f2bf(float f) {
    unsigned int u = __float_as_uint(f);
    u += 0x7fffu + ((u >> 16) & 1u);
    return (unsigned short)(u >> 16);
}

__device__ __forceinline__ float gelu_f(float v) {
    // tanh-form gelu; |err| vs exact erf-gelu < ~3e-3, negligible after @W2*c^-0.5
    float u = 0.7978845608028654f * v * (1.0f + 0.044715f * v * v);
    float a = fabsf(u);
    float e = __expf(-2.0f * a);
    float th = (1.0f - e) * __builtin_amdgcn_rcpf(1.0f + e);
    th = (u >= 0.0f) ? th : -th;
    return 0.5f * v * (1.0f + th);
}

// ---------------- kernel A: Kh/Qh/Vh (4 tokens/block) + fused W1^T bf16 pack ----------------
__global__ __launch_bounds__(128) void prep_kernel(const float* __restrict__ x,
                                                   const float* __restrict__ W1,
                                                   const float* __restrict__ b1,
                                                   const float* __restrict__ Wv,
                                                   const float* __restrict__ bv,
                                                   float* __restrict__ Kh,
                                                   float* __restrict__ Qh,
                                                   float* __restrict__ Vh,
                                                   unsigned short* __restrict__ w1t) {
    int t = threadIdx.x;  // 0..127

    // fused pack: 256 blocks x 128 threads == 32768 = all of w1t (h*256+d layout)
    {
        int e = blockIdx.x * 128 + t;
        int h = e >> 8, d = e & 255;
        w1t[e] = f2bf(W1[(size_t)d * 128 + h]);
    }

    int bi0 = blockIdx.x * 4;  // 4 tokens per block (flat over b*512+t)
    __shared__ float xr[4][128];
#pragma unroll
    for (int k = 0; k < 4; ++k) xr[k][t] = x[(size_t)(bi0 + k) * 128 + t];
    __syncthreads();

    float bq = b1[t];
    float aK[4] = {0.f, 0.f, 0.f, 0.f};
    float aQ[4] = {bq, bq, bq, bq};
#pragma unroll 4
    for (int d = 0; d < 128; ++d) {
        float w1k = W1[d * 128 + t];
        float w1q = W1[(128 + d) * 128 + t];
#pragma unroll
        for (int k = 0; k < 4; ++k) {
            aK[k] = fmaf(xr[k][d], w1k, aK[k]);
            aQ[k] = fmaf(xr[k][d], w1q, aQ[k]);
        }
    }
#pragma unroll
    for (int k = 0; k < 4; ++k) {
        Kh[(size_t)(bi0 + k) * 128 + t] = aK[k];
        Qh[(size_t)(bi0 + k) * 128 + t] = aQ[k];
    }

    // V: threads 0..63 -> tokens 0,1 ; threads 64..127 -> tokens 2,3
    int hs = t & 63, kb = (t >> 6) * 2;
    float bvv = bv[hs];
    float aV0 = bvv, aV1 = bvv;
#pragma unroll 4
    for (int d = 0; d < 128; ++d) {
        float wv = Wv[d * 64 + hs];
        aV0 = fmaf(xr[kb][d], wv, aV0);
        aV1 = fmaf(xr[kb + 1][d], wv, aV1);
    }
    Vh[(size_t)(bi0 + kb) * 64 + hs] = aV0;
    Vh[(size_t)(bi0 + kb + 1) * 64 + hs] = aV1;
}

// ---------------- kernel B: scores[b,i,j] for causal 8x8 tiles ----------------
// P = pde@W1 via 16x16x32 bf16 MFMA (batch-shared), epilogue gelu(P+Kh+Qh)@W2.
__global__ __launch_bounds__(256, 2) void score_kernel(const float* __restrict__ pde,
                                                       const unsigned short* __restrict__ w1t,
                                                       const float* __restrict__ Kh,
                                                       const float* __restrict__ Qh,
                                                       const float* __restrict__ W2,
                                                       const float* __restrict__ b2,
                                                       float* __restrict__ scores) {
    __shared__ unsigned short lw[128 * 256];  // 64 KB, XOR-swizzled W1^T bf16
    int tid = threadIdx.x;

    // stage W1^T -> LDS with 16B-chunk XOR swizzle (chunk p = c ^ (row&15))
#pragma unroll
    for (int it = 0; it < 16; ++it) {
        int chunk = it * 256 + tid;        // 4096 chunks of 16B
        int n = chunk >> 5, cc = chunk & 31;
        int4 v = ((const int4*)w1t)[chunk];
        ((int4*)lw)[n * 32 + (cc ^ (n & 15))] = v;
    }

    // triangular tile index -> (I,J), J<=I
    int tI = blockIdx.x;
    int I = (int)((sqrtf(8.0f * (float)tI + 1.0f) - 1.0f) * 0.5f);
    while ((I + 1) * (I + 2) / 2 <= tI) ++I;
    while (I * (I + 1) / 2 > tI) --I;
    int J = tI - I * (I + 1) / 2;
    int i0 = I * 8, j0 = J * 8;

    int w = tid >> 6, l = tid & 63;
    int c = l & 15, q = l >> 4;

    // A operand: row m = l&15 -> pair p = w*16 + m -> (i,j)
    int pl = w * 16 + c;
    int ai = i0 + (pl >> 3), aj = j0 + (pl & 7);
    const float* arow = pde + ((size_t)ai * TT + (size_t)aj) * 256 + q * 8;

    // preload this wave's whole pde slice (each element used exactly once)
    float4 araw[16];
#pragma unroll
    for (int ks = 0; ks < 8; ++ks) {
        araw[2 * ks] = *(const float4*)(arow + ks * 32);
        araw[2 * ks + 1] = *(const float4*)(arow + ks * 32 + 4);
    }

    // prefetch epilogue operands (hide L2 latency under MFMA/LDS work)
    int i_g = i0 + 2 * w + (q >> 1);
    int jb = j0 + 4 * (q & 1);
    float w2v[8], qh[2][8];
#pragma unroll
    for (int nt = 0; nt < 8; ++nt) w2v[nt] = W2[nt * 16 + c];
    float b2v = b2[0];
#pragma unroll
    for (int b = 0; b < 2; ++b) {
        const float* qrow = Qh + ((size_t)(b * TT) + i_g) * 128;
#pragma unroll
        for (int nt = 0; nt < 8; ++nt) qh[b][nt] = qrow[nt * 16 + c];
    }

    f32x4 acc[8];
#pragma unroll
    for (int nt = 0; nt < 8; ++nt) acc[nt] = (f32x4){0.f, 0.f, 0.f, 0.f};

    __syncthreads();

#pragma unroll
    for (int ks = 0; ks < 8; ++ks) {
        float4 a0 = araw[2 * ks], a1 = araw[2 * ks + 1];
        short8 afrag;
        afrag[0] = (short)f2bf(a0.x); afrag[1] = (short)f2bf(a0.y);
        afrag[2] = (short)f2bf(a0.z); afrag[3] = (short)f2bf(a0.w);
        afrag[4] = (short)f2bf(a1.x); afrag[5] = (short)f2bf(a1.y);
        afrag[6] = (short)f2bf(a1.z); afrag[7] = (short)f2bf(a1.w);
#pragma unroll
        for (int nt = 0; nt < 8; ++nt) {
            int n = nt * 16 + c;
            int p = (ks * 4 + q) ^ c;
            short8 bfrag = *(const short8*)&lw[n * 256 + p * 8];
            acc[nt] = __builtin_amdgcn_mfma_f32_16x16x32_bf16(afrag, bfrag, acc[nt], 0, 0, 0);
        }
    }

    // epilogue: D row m = 4q+r, col n = nt*16+c ; pair p = w*16+m
    const float invs = 0.08838834764831845f;  // 128^-0.5
#pragma unroll
    for (int b = 0; b < 2; ++b) {
#pragma unroll
        for (int r = 0; r < 4; ++r) {
            int j_g = jb + r;
            const float* krow = Kh + ((size_t)(b * TT) + j_g) * 128;
            float s = 0.f;
#pragma unroll
            for (int nt = 0; nt < 8; ++nt) {
                float v = acc[nt][r] + qh[b][nt] + krow[nt * 16 + c];
                s = fmaf(gelu_f(v), w2v[nt], s);
            }
            s += __shfl_xor(s, 1);
            s += __shfl_xor(s, 2);
            s += __shfl_xor(s, 4);
            s += __shfl_xor(s, 8);
            if (c == 0) scores[((size_t)(b * TT) + i_g) * TT + j_g] = (s + b2v) * invs;
        }
    }
}

// ---------------- kernel C: causal softmax + wei@Vh, 2 rows per block (Vh reuse x2) ----------------
__global__ __launch_bounds__(256) void softmax_pv_kernel(const float* __restrict__ scores,
                                                         const float* __restrict__ Vh,
                                                         float* __restrict__ out) {
    int blk = blockIdx.x;        // 0..511
    int b = blk >> 8;
    int i0 = (blk & 255) * 2;    // rows i0, i0+1
    const float* s0 = scores + ((size_t)(b * TT) + i0) * TT;
    __shared__ float e0[TT], e1[TT];
    __shared__ float redm[2][4], reds[2][4];
    __shared__ float pvred[4][2][64];
    int t = threadIdx.x;
    int lane = t & 63, wv = t >> 6;

    float m0 = -INFINITY, m1 = -INFINITY;
    for (int j = t; j < TT; j += 256) {
        if (j <= i0) m0 = fmaxf(m0, s0[j]);
        if (j <= i0 + 1) m1 = fmaxf(m1, s0[TT + j]);
    }
#pragma unroll
    for (int o = 32; o > 0; o >>= 1) {
        m0 = fmaxf(m0, __shfl_xor(m0, o));
        m1 = fmaxf(m1, __shfl_xor(m1, o));
    }
    if (lane == 0) { redm[0][wv] = m0; redm[1][wv] = m1; }
    __syncthreads();
    m0 = fmaxf(fmaxf(redm[0][0], redm[0][1]), fmaxf(redm[0][2], redm[0][3]));
    m1 = fmaxf(fmaxf(redm[1][0], redm[1][1]), fmaxf(redm[1][2], redm[1][3]));

    float t0 = 0.f, t1 = 0.f;
    for (int j = t; j < TT; j += 256) {
        float a = 0.f, bb = 0.f;
        if (j <= i0) a = __expf(s0[j] - m0);
        if (j <= i0 + 1) bb = __expf(s0[TT + j] - m1);
        e0[j] = a;
        e1[j] = bb;
        t0 += a;
        t1 += bb;
    }
#pragma unroll
    for (int o = 32; o > 0; o >>= 1) {
        t0 += __shfl_xor(t0, o);
        t1 += __shfl_xor(t1, o);
    }
    if (lane == 0) { reds[0][wv] = t0; reds[1][wv] = t1; }
    __syncthreads();
    float inv0 = __builtin_amdgcn_rcpf(reds[0][0] + reds[0][1] + reds[0][2] + reds[0][3]);
    float inv1 = __builtin_amdgcn_rcpf(reds[1][0] + reds[1][1] + reds[1][2] + reds[1][3]);

    // PV: each Vh row read once, feeds both output rows (e-bufs carry causal zeros)
    int hs = t & 63, ch = t >> 6;
    const float* vb = Vh + (size_t)b * TT * 64;
    float a0 = 0.f, a1 = 0.f;
    int j0 = ch * 128;
    for (int j = j0; j < j0 + 128 && j <= i0 + 1; ++j) {
        float v = vb[j * 64 + hs];
        a0 = fmaf(e0[j], v, a0);
        a1 = fmaf(e1[j], v, a1);
    }
    pvred[ch][0][hs] = a0;
    pvred[ch][1][hs] = a1;
    __syncthreads();
    if (t < 128) {
        int r = t >> 6, hh = t & 63;
        float s = pvred[0][r][hh] + pvred[1][r][hh] + pvred[2][r][hh] + pvred[3][r][hh];
        out[((size_t)(b * TT) + i0 + r) * 64 + hh] = s * (r ? inv1 : inv0);
    }
}

extern "C" void kernel_launch(void* const* d_in, const int* in_sizes, int n_in,
                              void* d_out, int out_size, void* d_ws, size_t ws_size,
                              hipStream_t stream) {
    const float* x = (const float*)d_in[0];
    // d_in[1] = pos_emb (unused by reference)
    const float* pde = (const float*)d_in[2];
    const float* W1 = (const float*)d_in[3];
    const float* b1 = (const float*)d_in[4];
    const float* W2 = (const float*)d_in[5];
    const float* b2 = (const float*)d_in[6];
    const float* Wv = (const float*)d_in[7];
    const float* bv = (const float*)d_in[8];
    float* out = (float*)d_out;

    char* ws = (char*)d_ws;
    float* scores = (float*)(ws);                       // 2*512*512*4 = 2 MB
    float* Kh = (float*)(ws + 2097152);                 // 512 KB
    float* Qh = (float*)(ws + 2621440);                 // 512 KB
    float* Vh = (float*)(ws + 3145728);                 // 256 KB
    unsigned short* w1t = (unsigned short*)(ws + 3407872);  // 64 KB

    prep_kernel<<<256, 128, 0, stream>>>(x, W1, b1, Wv, bv, Kh, Qh, Vh, w1t);
    score_kernel<<<2080, 256, 0, stream>>>(pde, w1t, Kh, Qh, W2, b2, scores);
    softmax_pv_kernel<<<512, 256, 0, stream>>>(scores, Vh, out);
}

// Round 4
// 389.923 us; speedup vs baseline: 1.0657x; 1.0657x over previous
//
#include <hip/hip_runtime.h>

#define TT 512

typedef short short8 __attribute__((ext_vector_type(8)));
typedef float f32x4 __attribute__((ext_vector_type(4)));

__device__ __forceinline__ unsigned short f2bf(float f) {
    unsigned int u = __float_as_uint(f);
    u += 0x7fffu + ((u >> 16) & 1u);
    return (unsigned short)(u >> 16);
}

__device__ __forceinline__ float gelu_f(float v) {
    // tanh-form gelu; |err| vs exact erf-gelu < ~3e-3, negligible after @W2*c^-0.5
    float u = 0.7978845608028654f * v * (1.0f + 0.044715f * v * v);
    float a = fabsf(u);
    float e = __expf(-2.0f * a);
    float th = (1.0f - e) * __builtin_amdgcn_rcpf(1.0f + e);
    th = (u >= 0.0f) ? th : -th;
    return 0.5f * v * (1.0f + th);
}

// ---------------- kernel A0: W1 (256x128) -> W1^T bf16 (128x256) ----------------
__global__ __launch_bounds__(256) void pack_w1t_kernel(const float* __restrict__ W1,
                                                       unsigned short* __restrict__ w1t) {
    int h = blockIdx.x;   // 0..127
    int d = threadIdx.x;  // 0..255
    w1t[(size_t)h * 256 + d] = f2bf(W1[(size_t)d * 128 + h]);
}

// ---------------- kernel A: Kh/Qh/Vh, 4 tokens per block (W1 reuse x4) ----------------
__global__ __launch_bounds__(128) void prep_kernel(const float* __restrict__ x,
                                                   const float* __restrict__ W1,
                                                   const float* __restrict__ b1,
                                                   const float* __restrict__ Wv,
                                                   const float* __restrict__ bv,
                                                   float* __restrict__ Kh,
                                                   float* __restrict__ Qh,
                                                   float* __restrict__ Vh) {
    int bi0 = blockIdx.x * 4;  // 256 blocks, 4 tokens each (tokens flat over b*512+t)
    int t = threadIdx.x;       // 0..127
    __shared__ float xr[4][128];
#pragma unroll
    for (int k = 0; k < 4; ++k) xr[k][t] = x[(size_t)(bi0 + k) * 128 + t];
    __syncthreads();

    float bq = b1[t];
    float aK[4] = {0.f, 0.f, 0.f, 0.f};
    float aQ[4] = {bq, bq, bq, bq};
#pragma unroll 4
    for (int d = 0; d < 128; ++d) {
        float w1k = W1[d * 128 + t];
        float w1q = W1[(128 + d) * 128 + t];
#pragma unroll
        for (int k = 0; k < 4; ++k) {
            aK[k] = fmaf(xr[k][d], w1k, aK[k]);
            aQ[k] = fmaf(xr[k][d], w1q, aQ[k]);
        }
    }
#pragma unroll
    for (int k = 0; k < 4; ++k) {
        Kh[(size_t)(bi0 + k) * 128 + t] = aK[k];
        Qh[(size_t)(bi0 + k) * 128 + t] = aQ[k];
    }

    // V: threads 0..63 -> tokens 0,1 ; threads 64..127 -> tokens 2,3
    int hs = t & 63, kb = (t >> 6) * 2;
    float bvv = bv[hs];
    float aV0 = bvv, aV1 = bvv;
#pragma unroll 4
    for (int d = 0; d < 128; ++d) {
        float wv = Wv[d * 64 + hs];
        aV0 = fmaf(xr[kb][d], wv, aV0);
        aV1 = fmaf(xr[kb + 1][d], wv, aV1);
    }
    Vh[(size_t)(bi0 + kb) * 64 + hs] = aV0;
    Vh[(size_t)(bi0 + kb + 1) * 64 + hs] = aV1;
}

// ---------------- kernel B: scores[b,i,j] for causal 8x8 tiles ----------------
// P = pde@W1 via 16x16x32 bf16 MFMA (batch-shared), epilogue gelu(P+Kh+Qh)@W2.
__global__ __launch_bounds__(256, 2) void score_kernel(const float* __restrict__ pde,
                                                       const unsigned short* __restrict__ w1t,
                                                       const float* __restrict__ Kh,
                                                       const float* __restrict__ Qh,
                                                       const float* __restrict__ W2,
                                                       const float* __restrict__ b2,
                                                       float* __restrict__ scores) {
    __shared__ unsigned short lw[128 * 256];  // 64 KB, XOR-swizzled W1^T bf16
    int tid = threadIdx.x;

    // stage W1^T -> LDS with 16B-chunk XOR swizzle (chunk p = c ^ (row&15))
#pragma unroll
    for (int it = 0; it < 16; ++it) {
        int chunk = it * 256 + tid;        // 4096 chunks of 16B
        int n = chunk >> 5, cc = chunk & 31;
        int4 v = ((const int4*)w1t)[chunk];
        ((int4*)lw)[n * 32 + (cc ^ (n & 15))] = v;
    }

    // triangular tile index -> (I,J), J<=I
    int tI = blockIdx.x;
    int I = (int)((sqrtf(8.0f * (float)tI + 1.0f) - 1.0f) * 0.5f);
    while ((I + 1) * (I + 2) / 2 <= tI) ++I;
    while (I * (I + 1) / 2 > tI) --I;
    int J = tI - I * (I + 1) / 2;
    int i0 = I * 8, j0 = J * 8;

    int w = tid >> 6, l = tid & 63;
    int c = l & 15, q = l >> 4;

    // A operand: row m = l&15 -> pair p = w*16 + m -> (i,j)
    int pl = w * 16 + c;
    int ai = i0 + (pl >> 3), aj = j0 + (pl & 7);
    const float* arow = pde + ((size_t)ai * TT + (size_t)aj) * 256 + q * 8;

    // preload this wave's whole pde slice (each element used exactly once)
    float4 araw[16];
#pragma unroll
    for (int ks = 0; ks < 8; ++ks) {
        araw[2 * ks] = *(const float4*)(arow + ks * 32);
        araw[2 * ks + 1] = *(const float4*)(arow + ks * 32 + 4);
    }

    // prefetch epilogue operands (hide L2 latency under MFMA/LDS work)
    int i_g = i0 + 2 * w + (q >> 1);
    int jb = j0 + 4 * (q & 1);
    float w2v[8], qh[2][8];
#pragma unroll
    for (int nt = 0; nt < 8; ++nt) w2v[nt] = W2[nt * 16 + c];
    float b2v = b2[0];
#pragma unroll
    for (int b = 0; b < 2; ++b) {
        const float* qrow = Qh + ((size_t)(b * TT) + i_g) * 128;
#pragma unroll
        for (int nt = 0; nt < 8; ++nt) qh[b][nt] = qrow[nt * 16 + c];
    }

    f32x4 acc[8];
#pragma unroll
    for (int nt = 0; nt < 8; ++nt) acc[nt] = (f32x4){0.f, 0.f, 0.f, 0.f};

    __syncthreads();

#pragma unroll
    for (int ks = 0; ks < 8; ++ks) {
        float4 a0 = araw[2 * ks], a1 = araw[2 * ks + 1];
        short8 afrag;
        afrag[0] = (short)f2bf(a0.x); afrag[1] = (short)f2bf(a0.y);
        afrag[2] = (short)f2bf(a0.z); afrag[3] = (short)f2bf(a0.w);
        afrag[4] = (short)f2bf(a1.x); afrag[5] = (short)f2bf(a1.y);
        afrag[6] = (short)f2bf(a1.z); afrag[7] = (short)f2bf(a1.w);
#pragma unroll
        for (int nt = 0; nt < 8; ++nt) {
            int n = nt * 16 + c;
            int p = (ks * 4 + q) ^ c;
            short8 bfrag = *(const short8*)&lw[n * 256 + p * 8];
            acc[nt] = __builtin_amdgcn_mfma_f32_16x16x32_bf16(afrag, bfrag, acc[nt], 0, 0, 0);
        }
    }

    // epilogue: D row m = 4q+r, col n = nt*16+c ; pair p = w*16+m
    const float invs = 0.08838834764831845f;  // 128^-0.5
#pragma unroll
    for (int b = 0; b < 2; ++b) {
#pragma unroll
        for (int r = 0; r < 4; ++r) {
            int j_g = jb + r;
            const float* krow = Kh + ((size_t)(b * TT) + j_g) * 128;
            float s = 0.f;
#pragma unroll
            for (int nt = 0; nt < 8; ++nt) {
                float v = acc[nt][r] + qh[b][nt] + krow[nt * 16 + c];
                s = fmaf(gelu_f(v), w2v[nt], s);
            }
            s += __shfl_xor(s, 1);
            s += __shfl_xor(s, 2);
            s += __shfl_xor(s, 4);
            s += __shfl_xor(s, 8);
            if (c == 0) scores[((size_t)(b * TT) + i_g) * TT + j_g] = (s + b2v) * invs;
        }
    }
}

// ---------------- kernel C: causal softmax over j + wei@Vh ----------------
__global__ __launch_bounds__(256) void softmax_pv_kernel(const float* __restrict__ scores,
                                                         const float* __restrict__ Vh,
                                                         float* __restrict__ out) {
    int bi = blockIdx.x;  // b*512 + i
    int b = bi >> 9, i = bi & 511;
    const float* srow = scores + (size_t)bi * TT;
    __shared__ float ebuf[TT];
    __shared__ float red[8];
    __shared__ float pvred[4][64];
    int t = threadIdx.x;
    int lane = t & 63, wv = t >> 6;

    float m = -INFINITY;
    for (int j = t; j < TT; j += 256)
        if (j <= i) m = fmaxf(m, srow[j]);
#pragma unroll
    for (int o = 32; o > 0; o >>= 1) m = fmaxf(m, __shfl_xor(m, o));
    if (lane == 0) red[wv] = m;
    __syncthreads();
    m = fmaxf(fmaxf(red[0], red[1]), fmaxf(red[2], red[3]));

    float s = 0.f;
    for (int j = t; j < TT; j += 256) {
        float e = 0.f;
        if (j <= i) e = __expf(srow[j] - m);
        ebuf[j] = e;
        s += e;
    }
#pragma unroll
    for (int o = 32; o > 0; o >>= 1) s += __shfl_xor(s, o);
    if (lane == 0) red[4 + wv] = s;
    __syncthreads();
    float inv = __builtin_amdgcn_rcpf(red[4] + red[5] + red[6] + red[7]);

    // PV: branch-free inner (ebuf is 0 beyond i); uniform early-exit per chunk
    int hs = t & 63, ch = t >> 6;
    const float* vb = Vh + (size_t)b * TT * 64;
    float acc = 0.f;
    int j0 = ch * 128;
    for (int j = j0; j < j0 + 128 && j <= i; j += 4) {
        float4 e = *(const float4*)&ebuf[j];  // LDS broadcast read
        acc = fmaf(e.x, vb[(j + 0) * 64 + hs], acc);
        acc = fmaf(e.y, vb[(j + 1) * 64 + hs], acc);
        acc = fmaf(e.z, vb[(j + 2) * 64 + hs], acc);
        acc = fmaf(e.w, vb[(j + 3) * 64 + hs], acc);
    }
    pvred[ch][hs] = acc;
    __syncthreads();
    if (t < 64)
        out[(size_t)bi * 64 + t] =
            (pvred[0][t] + pvred[1][t] + pvred[2][t] + pvred[3][t]) * inv;
}

extern "C" void kernel_launch(void* const* d_in, const int* in_sizes, int n_in,
                              void* d_out, int out_size, void* d_ws, size_t ws_size,
                              hipStream_t stream) {
    const float* x = (const float*)d_in[0];
    // d_in[1] = pos_emb (unused by reference)
    const float* pde = (const float*)d_in[2];
    const float* W1 = (const float*)d_in[3];
    const float* b1 = (const float*)d_in[4];
    const float* W2 = (const float*)d_in[5];
    const float* b2 = (const float*)d_in[6];
    const float* Wv = (const float*)d_in[7];
    const float* bv = (const float*)d_in[8];
    float* out = (float*)d_out;

    char* ws = (char*)d_ws;
    float* scores = (float*)(ws);                       // 2*512*512*4 = 2 MB
    float* Kh = (float*)(ws + 2097152);                 // 512 KB
    float* Qh = (float*)(ws + 2621440);                 // 512 KB
    float* Vh = (float*)(ws + 3145728);                 // 256 KB
    unsigned short* w1t = (unsigned short*)(ws + 3407872);  // 64 KB

    pack_w1t_kernel<<<128, 256, 0, stream>>>(W1, w1t);
    prep_kernel<<<256, 128, 0, stream>>>(x, W1, b1, Wv, bv, Kh, Qh, Vh);
    score_kernel<<<2080, 256, 0, stream>>>(pde, w1t, Kh, Qh, W2, b2, scores);
    softmax_pv_kernel<<<1024, 256, 0, stream>>>(scores, Vh, out);
}